// Round 6
// baseline (661.030 us; speedup 1.0000x reference)
//
#include <hip/hip_runtime.h>
#include <hip/hip_bf16.h>

// Problem constants
#define B   16
#define H   24
#define W   96
#define C   1024
#define HID 256
#define V   5000
#define EMB 256
#define HW  (H*W)          // 2304
#define BN_EPS 1e-5f
#define H2  (H+2)          // 26 (halo-padded)
#define W2  (W+2)          // 98

// d_out layout (floats): output[B*V] | hidden[B*HID] | alpha[B*HW] | att_sum[B*HW]
#define OUT0 0
#define OUT1 (B*V)
#define OUT2 (OUT1 + B*HID)
#define OUT3 (OUT2 + B*HW)

// ws layout (bytes, 256-aligned)
#define WSB_IMGT  0                      // B*HW*C bf16      = 75,497,472
#define WSB_ETP   75497472               // B*H2*W2*256 bf16 = 20,873,216
#define WSB_WTB   96370688               // 9*256*256 bf16   =  1,179,648
#define WSB_UAT   97550336               // 256*1024 bf16    =    524,288
#define WSB_E     98074624               // 2*B*HW f32       =    294,912
#define WSB_ST1   98369536               // B*256 f32
#define WSB_CT    98385920               // B*1024 f32
#define WSB_PRE   98451456               // B*128 f32
#define WSB_GIGH1 98459648               // B*1536 f32
#define WSB_GH2   98574336               // B*896 f32
#define WSB_GI2   98631680               // 4*B*896 f32

typedef __attribute__((ext_vector_type(8))) short short8;
typedef __attribute__((ext_vector_type(4))) float f32x4;

__device__ inline unsigned short f2bf(float f) {
    union { float f; unsigned int u; } v; v.f = f;
    unsigned int r = v.u + 0x7fffu + ((v.u >> 16) & 1u);   // RNE
    return (unsigned short)(r >> 16);
}
__device__ inline float bf2f(unsigned short u) {
    union { unsigned int u; float f; } v; v.u = ((unsigned int)u) << 16;
    return v.f;
}

// async global(16B) -> LDS, no VGPR round-trip. LDS dest must be wave-uniform
// base; HW scatters lane i to base + i*16 (m104).
__device__ inline void gload_lds16(const unsigned short* g, unsigned short* l) {
    __builtin_amdgcn_global_load_lds(
        (const __attribute__((address_space(1))) void*)g,
        (__attribute__((address_space(3))) void*)l,
        16, 0, 0);
}

// ---------------- img fp32 [b][c][hw] -> bf16 [b][hw][c] (gather transpose, swizzled LDS) ----------------
__global__ __launch_bounds__(256) void k_imgT(const float* img, unsigned short* imgT)
{
    int hw0 = blockIdx.x*64, c0 = blockIdx.y*128, b = blockIdx.z;
    int t = threadIdx.x;
    __shared__ __align__(16) unsigned short tr[64*256];     // 32 KB
    int row = t & 63;
    int sgb = t >> 6;                                       // 0..3 (wave-uniform)
    const float* src = img + ((size_t)b*C + c0)*HW + hw0 + row;
    #pragma unroll
    for (int k = 0; k < 4; ++k) {
        int sg = sgb + k*4;                                 // 16B slot (8 channels)
        union { short8 v; unsigned short u[8]; } pk;
        #pragma unroll
        for (int j = 0; j < 8; ++j)
            pk.u[j] = f2bf(src[(size_t)(sg*8 + j)*HW]);
        *(short8*)&tr[row*256 + (sg ^ (row & 31))*8] = pk.v;
    }
    __syncthreads();
    #pragma unroll
    for (int k = 0; k < 4; ++k) {
        int i = k*256 + t;
        int orow = i >> 4, sg = i & 15;
        *(short8*)&imgT[((size_t)(b*HW) + hw0 + orow)*1024 + c0 + sg*8] =
            *(const short8*)&tr[orow*256 + (sg ^ (orow & 31))*8];
    }
}

// ---------------- k_prep: fused wtb-transpose | uat-transpose | attsum-conv | ct-zero | et_p halo-zero ----------------
__global__ __launch_bounds__(256) void k_prep(
    const float* conv_w_src, unsigned short* wtb,
    const float* ua_w, unsigned short* uat,
    const float* att_in, const float* alpha_t, const float* cw, const float* cb, float* att_out,
    float* ct, unsigned short* et_p)
{
    int x = blockIdx.x, t = threadIdx.x;
    if (x < 2304) {
        int idx = x*256 + t;                                // 9*256*256
        int c = idx & 255; int o = (idx >> 8) & 255; int khw = idx >> 16;
        wtb[(khw*256 + o)*256 + c] = f2bf(conv_w_src[(o*256 + c)*9 + khw]);
    } else if (x < 3328) {
        int idx = (x - 2304)*256 + t;                       // 256*1024
        int c = idx & 1023; int d = idx >> 10;
        uat[d*1024 + c] = f2bf(ua_w[c*256 + d]);
    } else if (x < 3472) {
        int i = (x - 3328)*256 + t;                         // B*HW
        int w = i % W; int h = (i / W) % H; int b = i / HW;
        float s = cb[0];
        #pragma unroll
        for (int kh = 0; kh < 3; ++kh) {
            int r = h + kh - 1; if (r < 0 || r >= H) continue;
            #pragma unroll
            for (int kw = 0; kw < 3; ++kw) {
                int c = w + kw - 1; if (c < 0 || c >= W) continue;
                s += alpha_t[(b*H + r)*W + c]*cw[kh*3+kw];
            }
        }
        att_out[i] = att_in[i] + s;
    } else if (x < 3536) {
        ct[(x - 3472)*256 + t] = 0.f;                       // B*C
    } else {
        // halo zero: 7808 int4 per b (row0: 3136, row25: 3136, side cols: 1536)
        int flat = (x - 3536)*256 + t;                      // < 124928
        int b = flat / 7808; int r = flat - b*7808;
        int h2, w2, j;
        if (r < 3136)      { h2 = 0;  w2 = r >> 5;          j = r & 31; }
        else if (r < 6272) { h2 = 25; w2 = (r - 3136) >> 5; j = (r - 3136) & 31; }
        else {
            int rr = r - 6272;                              // < 1536
            h2 = 1 + (rr >> 6);
            int s = rr & 63;
            w2 = (s < 32) ? 0 : 97;
            j = s & 31;
        }
        ((int4*)et_p)[((size_t)(b*H2 + h2)*W2 + w2)*32 + j] = make_int4(0,0,0,0);
    }
}

// ---------------- GRU1 matmuls: gigh[b][0:768]=emb@wi, [768:1536]=h0@wh ----------------
__global__ __launch_bounds__(256) void k_tail1(
    const int* y, const float* emb_table, const float* h0,
    const float* wi, const float* wh, float* gigh)
{
    int virt = blockIdx.x*16;            // 0..1535
    int t = threadIdx.x;
    bool gi_mode = virt < 768;
    __shared__ float a_l[16*256];
    for (int i = t; i < 4096; i += 256) {
        int b = i >> 8, k = i & 255;
        a_l[i] = gi_mode ? emb_table[y[b]*EMB + k] : h0[b*HID + k];
    }
    __syncthreads();
    int nl = t & 15, b = t >> 4;
    int n = (gi_mode ? virt : virt - 768) + nl;
    const float* wp = gi_mode ? wi : wh;
    float acc = 0.f;
    #pragma unroll 16
    for (int k = 0; k < 256; ++k) acc += a_l[b*256 + k]*wp[k*768 + n];
    gigh[b*1536 + virt + nl] = acc;
}

// ---------------- k_fc1c: GRU1 nonlinearity (in-block) + fc1 -> st1 ----------------
__global__ __launch_bounds__(256) void k_fc1c(
    const float* gigh, const float* h0, const float* bi, const float* bh,
    const float* fc1_w, const float* fc1_b, float* st1)
{
    int n0 = blockIdx.x*16, t = threadIdx.x;
    __shared__ float a_l[16*256];
    for (int i = t; i < 4096; i += 256) {
        int b = i >> 8, k = i & 255;
        const float* g = gigh + b*1536;
        float ir = g[k] + bi[k], iz = g[256+k] + bi[256+k], in_ = g[512+k] + bi[512+k];
        float hr = g[768+k] + bh[k], hz = g[1024+k] + bh[256+k], hn = g[1280+k] + bh[512+k];
        float r = 1.f/(1.f+__expf(-(ir+hr)));
        float z = 1.f/(1.f+__expf(-(iz+hz)));
        float n = tanhf(in_ + r*hn);
        a_l[i] = (1.f - z)*n + z*h0[b*HID + k];
    }
    __syncthreads();
    int nl = t & 15, b = t >> 4;
    float acc = fc1_b[n0+nl];
    #pragma unroll 16
    for (int k = 0; k < 256; ++k) acc += a_l[b*256+k]*fc1_w[k*256 + n0 + nl];
    st1[b*256 + n0 + nl] = acc;
}

// ---------------- K4: MFMA GEMM et = imgT @ ua_w + epilogue -> bf16 NHWC halo-padded ----------------
// M-split: 48 rows/block, grid 1536 = 6/CU (was 768 = 3/CU grid-limited at 33% occ).
// Waves 1m x 4n (48m x 32n): 3 A ds_reads + 2 B glb per cs (cheap-B ratio).
// LDS 128-ch chunks, dbuf 24.6 KB -> 6 blocks resident. Async gload_lds staging,
// linear dest + pre-swizzled source; read slot = (q|(cs>>3)) ^ (m&7) -> 8 lanes
// per bank-granule-group = conflict-free; addr folds to ebase ^ cs.
__global__ __launch_bounds__(256, 6) void k_et(
    const unsigned short* imgT, const unsigned short* uat, const float* ua_b,
    const float* st1, const float* att_sum, const float* uf_w, const float* uf_b,
    unsigned short* et_p)
{
    int hb = blockIdx.x; int h = hb >> 1, mh = hb & 1;
    int ny = blockIdx.y, b = blockIdx.z;
    int t = threadIdx.x;
    int wv = t >> 6, lane = t & 63, q = lane >> 4, ln = lane & 15;
    int n0 = ny*128 + wv*32;
    __shared__ __align__(16) unsigned short a_l[2*6144];    // 2 x 12.3 KB

    f32x4 acc[6];                                           // [mf*2 + j]
    #pragma unroll
    for (int i = 0; i < 6; ++i) acc[i] = (f32x4){0.f,0.f,0.f,0.f};

    const unsigned short* ab = imgT + ((size_t)(b*HW) + h*W + mh*48)*1024;
    const unsigned short* bbase = uat + (size_t)(n0 + ln)*1024 + q*8;

    int ebase[3];
    #pragma unroll
    for (int mf = 0; mf < 3; ++mf) {
        int m = ln + 16*mf;
        ebase[mf] = m*128 + (q ^ (m & 7))*8;
    }

    // staging: 768 slots/chunk, 12 issues; wave wv does g = wv + 4*it (it 0..2)
    int goff[3], loff[3];
    #pragma unroll
    for (int it = 0; it < 3; ++it) {
        int g = wv + it*4;
        int L = g*64 + lane;                                // 0..767
        int m = L >> 4, s = L & 15;
        int sig = (s & 8) | ((s ^ m) & 7);
        goff[it] = m*1024 + sig*8;
        loff[it] = g*512;                                   // shorts, wave-uniform
    }

    #pragma unroll
    for (int it = 0; it < 3; ++it)
        gload_lds16(ab + goff[it], &a_l[loff[it]]);
    __syncthreads();

    int cur = 0;
    for (int c0 = 0; c0 < 1024; c0 += 128) {
        int bufS = cur*6144, nbufS = bufS ^ 6144;
        if (c0 < 896) {
            #pragma unroll
            for (int it = 0; it < 3; ++it)
                gload_lds16(ab + goff[it] + c0 + 128, &a_l[nbufS + loff[it]]);
        }
        #pragma unroll
        for (int cs = 0; cs < 128; cs += 32) {
            short8 av[3];
            #pragma unroll
            for (int mf = 0; mf < 3; ++mf)
                av[mf] = *(const short8*)&a_l[bufS + (ebase[mf] ^ cs)];
            #pragma unroll
            for (int j = 0; j < 2; ++j) {
                short8 bv = *(const short8*)(bbase + (size_t)(j*16)*1024 + c0 + cs);
                #pragma unroll
                for (int mf = 0; mf < 3; ++mf)
                    acc[mf*2+j] = __builtin_amdgcn_mfma_f32_16x16x32_bf16(av[mf], bv, acc[mf*2+j], 0, 0, 0);
            }
        }
        __syncthreads();                                    // drains vmcnt + barrier
        cur ^= 1;
    }

    float att_m[12];
    #pragma unroll
    for (int mf = 0; mf < 3; ++mf)
        #pragma unroll
        for (int r = 0; r < 4; ++r)
            att_m[mf*4+r] = att_sum[(b*H + h)*W + mh*48 + mf*16 + q*4 + r];
    #pragma unroll
    for (int j = 0; j < 2; ++j) {
        int n = n0 + j*16 + ln;
        float s1 = st1[b*256 + n] + ua_b[n];
        float ufw = uf_w[n], ufb = uf_b[n];
        #pragma unroll
        for (int mf = 0; mf < 3; ++mf)
            #pragma unroll
            for (int r = 0; r < 4; ++r) {
                int m = mh*48 + mf*16 + q*4 + r;
                float v = acc[mf*2+j][r] + s1 + att_m[mf*4+r]*ufw + ufb;
                et_p[((size_t)(b*H2 + h + 1)*W2 + (m + 1))*256 + n] = f2bf(v);
            }
    }
}

// ---------------- K5: MFMA conv(3x3,256->256) + BN + tanh + v-dot -> e_part[ny][b,h,w] ----------------
// M-split on w: 48 cols/block (+2 halo), grid 1536 = 6/CU. Waves 1m x 4n (48m x 32n).
// Patch/chunk = 3 planes x 50 rows x 32 ch = 9.6 KB, dbuf 19.2 KB -> 6 blocks resident.
// Async gload_lds, linear dest + pre-swizzled source; read slot = q ^ (x2&3) ->
// 8 lanes/granule-group = conflict-free.
__global__ __launch_bounds__(256, 6) void k_conv(
    const unsigned short* et_p, const unsigned short* wtb, const float* cb,
    const float* bn_g, const float* bn_b, const float* bn_m, const float* bn_v,
    const float* v_w, float* e_part)
{
    int hb = blockIdx.x; int h = hb >> 1, mh = hb & 1;
    int ny = blockIdx.y, b = blockIdx.z;
    int t = threadIdx.x;
    int wv = t >> 6, lane = t & 63, q = lane >> 4, ln = lane & 15;
    int n0 = ny*128 + wv*32;
    __shared__ __align__(16) unsigned short patch[2*4800];  // 2 x 9.6 KB
    __shared__ float lds_red[4][48];

    f32x4 acc[6];                                           // [mf*2 + j]
    #pragma unroll
    for (int i = 0; i < 6; ++i) acc[i] = (f32x4){0.f,0.f,0.f,0.f};

    int abase[3][3];                                        // shorts, within plane (stride 1600)
    #pragma unroll
    for (int mf = 0; mf < 3; ++mf)
        #pragma unroll
        for (int kw = 0; kw < 3; ++kw) {
            int x2 = ln + 16*mf + kw;                       // 0..49 local
            abase[mf][kw] = x2*32 + (q ^ (x2 & 3))*8;
        }

    const unsigned short* gb = et_p + ((size_t)(b*H2 + h)*W2 + mh*48)*256;
    const unsigned short* wb = wtb + (size_t)(n0 + ln)*256 + q*8;

    // staging: 600 slots/chunk (3 x 50 x 4), 10 issues; wave wv: g = wv + 4*it;
    // g=9 partial (24 lanes); waves 2,3 skip it=2.
    int goff[3], loff[3]; bool la[3];
    #pragma unroll
    for (int it = 0; it < 3; ++it) {
        int g = wv + it*4;
        int L = g*64 + lane;
        la[it] = (g < 10) && (L < 600);
        int Lc = la[it] ? L : 0;
        int pl = Lc / 200; int rem = Lc - pl*200;
        int x2 = rem >> 2, s = rem & 3;
        goff[it] = (pl*W2 + x2)*256 + (s ^ (x2 & 3))*8;
        loff[it] = g*512;                                   // shorts, wave-uniform
    }

    #pragma unroll
    for (int it = 0; it < 3; ++it)
        if (la[it]) gload_lds16(gb + goff[it], &patch[loff[it]]);
    __syncthreads();

    int cur = 0;
    for (int cc = 0; cc < 8; ++cc) {
        int bufS = cur*4800, nbufS = bufS ^ 4800;
        if (cc < 7) {
            int c1 = (cc + 1)*32;
            #pragma unroll
            for (int it = 0; it < 3; ++it)
                if (la[it]) gload_lds16(gb + goff[it] + c1, &patch[nbufS + loff[it]]);
        }
        int c0 = cc*32;
        #pragma unroll
        for (int kh = 0; kh < 3; ++kh) {
            #pragma unroll
            for (int kw = 0; kw < 3; ++kw) {
                short8 av[3];
                #pragma unroll
                for (int mf = 0; mf < 3; ++mf)
                    av[mf] = *(const short8*)&patch[bufS + kh*1600 + abase[mf][kw]];
                const unsigned short* brow = wb + (size_t)(kh*3 + kw)*65536 + c0;
                #pragma unroll
                for (int j = 0; j < 2; ++j) {
                    short8 bv = *(const short8*)(brow + j*4096);
                    #pragma unroll
                    for (int mf = 0; mf < 3; ++mf)
                        acc[mf*2+j] = __builtin_amdgcn_mfma_f32_16x16x32_bf16(av[mf], bv, acc[mf*2+j], 0, 0, 0);
                }
            }
        }
        __syncthreads();                                    // drains vmcnt + barrier
        cur ^= 1;
    }

    float psum[12];
    #pragma unroll
    for (int i = 0; i < 12; ++i) psum[i] = 0.f;
    #pragma unroll
    for (int j = 0; j < 2; ++j) {
        int o = n0 + j*16 + ln;
        float inv  = bn_g[o]*rsqrtf(bn_v[o] + BN_EPS);
        float mean = bn_m[o], beta = bn_b[o], bias = cb[o], vw = v_w[o];
        #pragma unroll
        for (int mf = 0; mf < 3; ++mf)
            #pragma unroll
            for (int r = 0; r < 4; ++r) {
                float x = (acc[mf*2+j][r] + bias - mean)*inv + beta;
                x = fminf(fmaxf(x, -15.f), 15.f);
                float ex = __expf(2.f*x);
                psum[mf*4+r] += ((ex - 1.f)/(ex + 1.f))*vw;
            }
    }
    #pragma unroll
    for (int s = 1; s < 16; s <<= 1)
        #pragma unroll
        for (int i = 0; i < 12; ++i) psum[i] += __shfl_xor(psum[i], s);
    if (ln == 0) {
        #pragma unroll
        for (int mf = 0; mf < 3; ++mf)
            #pragma unroll
            for (int r = 0; r < 4; ++r)
                lds_red[wv][mf*16 + q*4 + r] = psum[mf*4+r];
    }
    __syncthreads();
    if (t < 48)
        e_part[(size_t)ny*(B*HW) + (b*H + h)*W + mh*48 + t] =
            lds_red[0][t] + lds_red[1][t] + lds_red[2][t] + lds_red[3][t];
}

// ---------------- K6: masked softmax over (h,w) -> alpha (sums the two e partials) ----------------
__global__ __launch_bounds__(256) void k_softmax(
    const float* e_part, const int* h_mask, const int* w_mask, const float* v_b,
    float* alpha_out)
{
    int b = blockIdx.x, t = threadIdx.x;
    int hm = h_mask[b], wm = w_mask[b];
    float vb = v_b[0];
    __shared__ float red[256];
    float vals[9];
    float loc = 0.f;
    #pragma unroll
    for (int i = 0; i < 9; ++i) {
        int hw = t + i*256;
        int hh = hw / W, ww = hw % W;
        float v = 0.f;
        if (hh < hm && ww < wm)
            v = __expf(e_part[b*HW + hw] + e_part[B*HW + b*HW + hw] + vb);
        vals[i] = v; loc += v;
    }
    red[t] = loc; __syncthreads();
    for (int s = 128; s > 0; s >>= 1) { if (t < s) red[t] += red[t+s]; __syncthreads(); }
    float inv = 1.f/(red[0] + 1e-8f);
    #pragma unroll
    for (int i = 0; i < 9; ++i) alpha_out[b*HW + t + i*256] = vals[i]*inv;
}

// ---------------- K7: ct[b,c] += sum_hw alpha[b,hw]*imgT[b,hw,c] (bf16 A, fp32 acc, atomics) ----------------
// 64 hw-splits -> 1024 blocks = 4/CU (was 16 splits = 1/CU, latency-starved).
__global__ __launch_bounds__(256) void k_ct(
    const float* alpha, const unsigned short* imgT, float* ct)
{
    int s = blockIdx.x, b = blockIdx.y, t = threadIdx.x;
    int cg = (t & 127)*8, half = t >> 7;
    float acc[8];
    #pragma unroll
    for (int j = 0; j < 8; ++j) acc[j] = 0.f;
    for (int i = 0; i < 18; ++i) {
        int hw = s*36 + i*2 + half;
        float a = alpha[b*HW + hw];
        union { short8 v; unsigned short u[8]; } pk;
        pk.v = *(const short8*)&imgT[((size_t)(b*HW) + hw)*1024 + cg];
        #pragma unroll
        for (int j = 0; j < 8; ++j) acc[j] += a*bf2f(pk.u[j]);
    }
    #pragma unroll
    for (int j = 0; j < 8; ++j) atomicAdd(&ct[b*1024 + cg + j], acc[j]);
}

// ---------------- k_g2: fused GRU2 h-side+pemb | GRU2 i-side+wc (split-K) ----------------
__global__ __launch_bounds__(256) void k_g2(
    const float* st1, const int* y, const float* emb_table,
    const float* wh, const float* emb2_w, float* gh2,
    const float* ct, const float* wi, const float* wc_w, float* gi2p)
{
    int x = blockIdx.x, t = threadIdx.x;
    __shared__ float a_l[16*256];
    if (x < 56) {
        int virt = x*16;
        bool ghm = virt < 768;
        for (int i = t; i < 4096; i += 256) {
            int b = i >> 8, k = i & 255;
            a_l[i] = ghm ? st1[b*256 + k] : emb_table[y[b]*EMB + k];
        }
        __syncthreads();
        int nl = t & 15, b = t >> 4;
        float acc = 0.f;
        if (ghm) {
            int n = virt + nl;
            #pragma unroll 16
            for (int k = 0; k < 256; ++k) acc += a_l[b*256+k]*wh[k*768 + n];
        } else {
            int n = virt - 768 + nl;
            #pragma unroll 16
            for (int k = 0; k < 256; ++k) acc += a_l[b*256+k]*emb2_w[k*128 + n];
        }
        gh2[b*896 + virt + nl] = acc;
    } else {
        int xx = x - 56;
        int ks = xx / 56, virt = (xx - ks*56)*16;
        int k0 = ks*256;
        for (int i = t; i < 4096; i += 256) {
            int b = i >> 8, k = i & 255;
            a_l[i] = ct[b*1024 + k0 + k];
        }
        __syncthreads();
        int nl = t & 15, b = t >> 4;
        float acc = 0.f;
        if (virt < 768) {
            int n = virt + nl;
            #pragma unroll 16
            for (int k = 0; k < 256; ++k) acc += a_l[b*256+k]*wi[(k0+k)*768 + n];
        } else {
            int n = virt - 768 + nl;
            #pragma unroll 16
            for (int k = 0; k < 256; ++k) acc += a_l[b*256+k]*wc_w[(k0+k)*128 + n];
        }
        gi2p[(ks*16 + b)*896 + virt + nl] = acc;
    }
}

// ---------------- k_fc2c: GRU2 nonlinearity (in-block) + hidden write + pre ----------------
__global__ __launch_bounds__(256) void k_fc2c(
    const float* gi2p, const float* gh2, const float* st1,
    const float* bi, const float* bh,
    const float* fc2_w, const float* fc2_b, const float* emb2_b, const float* wc_b,
    float* hidden_out, float* pre)
{
    int n0 = blockIdx.x*16, t = threadIdx.x;
    __shared__ float st_l[16*256];
    for (int i = t; i < 4096; i += 256) {
        int b = i >> 8, k = i & 255;
        float ir = bi[k], iz = bi[256+k], in_ = bi[512+k];
        #pragma unroll
        for (int ks = 0; ks < 4; ++ks) {
            const float* g = gi2p + (ks*16 + b)*896;
            ir += g[k]; iz += g[256+k]; in_ += g[512+k];
        }
        const float* gh = gh2 + b*896;
        float hr = gh[k] + bh[k], hz = gh[256+k] + bh[256+k], hn = gh[512+k] + bh[512+k];
        float h = st1[b*256+k];
        float r = 1.f/(1.f+__expf(-(ir+hr)));
        float z = 1.f/(1.f+__expf(-(iz+hz)));
        float n = tanhf(in_ + r*hn);
        float s = (1.f - z)*n + z*h;
        st_l[i] = s;
        if (blockIdx.x == 0) hidden_out[b*HID + k] = s;
    }
    __syncthreads();
    int nl = t & 15, b = t >> 4;
    int n = n0 + nl;
    float acc = fc2_b[n] + emb2_b[n] + wc_b[n] + gh2[b*896 + 768 + n];
    #pragma unroll
    for (int ks = 0; ks < 4; ++ks) acc += gi2p[(ks*16 + b)*896 + 768 + n];
    #pragma unroll 16
    for (int k = 0; k < 256; ++k) acc += st_l[b*256+k]*fc2_w[k*128 + n];
    pre[b*128 + n] = acc;
}

// ---------------- logits (raw) = pre @ out_w + out_b ----------------
__global__ __launch_bounds__(256) void k_logits(
    const float* pre, const float* out_w, const float* out_b, float* out)
{
    int j0 = blockIdx.x*64, t = threadIdx.x;
    __shared__ float pre_l[16*128];
    for (int i = t; i < 2048; i += 256) pre_l[i] = pre[i];
    __syncthreads();
    int jl = t & 63, bg = t >> 6;
    int j = j0 + jl;
    if (j >= V) return;
    float acc0=0.f, acc1=0.f, acc2=0.f, acc3=0.f;
    const float* pl = pre_l + bg*4*128;
    #pragma unroll 8
    for (int k = 0; k < 128; ++k) {
        float wv = out_w[k*V + j];
        acc0 += pl[k]*wv; acc1 += pl[128+k]*wv; acc2 += pl[256+k]*wv; acc3 += pl[384+k]*wv;
    }
    float ob = out_b[j];
    out[(bg*4+0)*V + j] = acc0 + ob;
    out[(bg*4+1)*V + j] = acc1 + ob;
    out[(bg*4+2)*V + j] = acc2 + ob;
    out[(bg*4+3)*V + j] = acc3 + ob;
}

// ---------------- in-place log_softmax over V per batch ----------------
__global__ __launch_bounds__(1024) void k_lsm(float* out)
{
    int b = blockIdx.x, t = threadIdx.x;
    __shared__ float red[1024];
    float lg[5]; float mx = -1e30f;
    #pragma unroll
    for (int i = 0; i < 5; ++i) {
        int j = t + i*1024;
        lg[i] = (j < V) ? out[b*V + j] : -1e30f;
        mx = fmaxf(mx, lg[i]);
    }
    red[t] = mx; __syncthreads();
    for (int s = 512; s > 0; s >>= 1) { if (t < s) red[t] = fmaxf(red[t], red[t+s]); __syncthreads(); }
    float gmax = red[0]; __syncthreads();
    float se = 0.f;
    #pragma unroll
    for (int i = 0; i < 5; ++i) { int j = t + i*1024; if (j < V) se += __expf(lg[i] - gmax); }
    red[t] = se; __syncthreads();
    for (int s = 512; s > 0; s >>= 1) { if (t < s) red[t] += red[t+s]; __syncthreads(); }
    float lse = logf(red[0]);
    #pragma unroll
    for (int i = 0; i < 5; ++i) { int j = t + i*1024; if (j < V) out[b*V + j] = lg[i] - gmax - lse; }
}

extern "C" void kernel_launch(void* const* d_in, const int* in_sizes, int n_in,
                              void* d_out, int out_size, void* d_ws, size_t ws_size,
                              hipStream_t stream)
{
    const int*   input_y      = (const int*)  d_in[0];
    const float* input_hidden = (const float*)d_in[1];
    const float* img          = (const float*)d_in[2];
    const float* attention    = (const float*)d_in[4];
    const float* alpha_t      = (const float*)d_in[5];
    const int*   h_mask       = (const int*)  d_in[8];
    const int*   w_mask       = (const int*)  d_in[9];
    const float* emb_table    = (const float*)d_in[10];
    const float* gru1_wi      = (const float*)d_in[11];
    const float* gru1_wh      = (const float*)d_in[12];
    const float* gru1_bi      = (const float*)d_in[13];
    const float* gru1_bh      = (const float*)d_in[14];
    const float* fc1_w        = (const float*)d_in[15];
    const float* fc1_b        = (const float*)d_in[16];
    const float* gru2_wi      = (const float*)d_in[17];
    const float* gru2_wh      = (const float*)d_in[18];
    const float* gru2_bi      = (const float*)d_in[19];
    const float* gru2_bh      = (const float*)d_in[20];
    const float* out_w        = (const float*)d_in[21];
    const float* out_b        = (const float*)d_in[22];
    const float* emb2_w       = (const float*)d_in[23];
    const float* emb2_b       = (const float*)d_in[24];
    const float* conv1_w      = (const float*)d_in[25];
    const float* conv1_b      = (const float*)d_in[26];
    const float* conv_tan_w   = (const float*)d_in[27];
    const float* conv_tan_b   = (const float*)d_in[28];
    const float* fc2_w        = (const float*)d_in[29];
    const float* fc2_b        = (const float*)d_in[30];
    const float* ua_w         = (const float*)d_in[31];
    const float* ua_b         = (const float*)d_in[32];
    const float* uf_w         = (const float*)d_in[33];
    const float* uf_b         = (const float*)d_in[34];
    const float* v_w          = (const float*)d_in[35];
    const float* v_b          = (const float*)d_in[36];
    const float* wc_w         = (const float*)d_in[37];
    const float* wc_b         = (const float*)d_in[38];
    const float* bn1_gamma    = (const float*)d_in[39];
    const float* bn1_beta     = (const float*)d_in[40];
    const float* bn1_mean     = (const float*)d_in[41];
    const float* bn1_var      = (const float*)d_in[42];

    float* out = (float*)d_out;
    char*  ws  = (char*)d_ws;
    unsigned short* imgT = (unsigned short*)(ws + WSB_IMGT);
    unsigned short* et_p = (unsigned short*)(ws + WSB_ETP);
    unsigned short* wtb  = (unsigned short*)(ws + WSB_WTB);
    unsigned short* uat  = (unsigned short*)(ws + WSB_UAT);
    float* e_part = (float*)(ws + WSB_E);
    float* st1   = (float*)(ws + WSB_ST1);
    float* ct    = (float*)(ws + WSB_CT);
    float* pre   = (float*)(ws + WSB_PRE);
    float* gigh1 = (float*)(ws + WSB_GIGH1);
    float* gh2   = (float*)(ws + WSB_GH2);
    float* gi2p  = (float*)(ws + WSB_GI2);

    float* out_logits = out + OUT0;
    float* out_hidden = out + OUT1;
    float* out_alpha  = out + OUT2;
    float* out_attsum = out + OUT3;

    k_imgT<<<dim3(HW/64, C/128, B), 256, 0, stream>>>(img, imgT);
    k_prep<<<4024, 256, 0, stream>>>(conv_tan_w, wtb, ua_w, uat,
                                     attention, alpha_t, conv1_w, conv1_b, out_attsum,
                                     ct, et_p);
    k_tail1<<<96, 256, 0, stream>>>(input_y, emb_table, input_hidden,
                                    gru1_wi, gru1_wh, gigh1);
    k_fc1c<<<16, 256, 0, stream>>>(gigh1, input_hidden, gru1_bi, gru1_bh,
                                   fc1_w, fc1_b, st1);
    k_et<<<dim3(H*2, 2, B), 256, 0, stream>>>(imgT, uat, ua_b, st1, out_attsum,
                                              uf_w, uf_b, et_p);
    k_conv<<<dim3(H*2, 2, B), 256, 0, stream>>>(et_p, wtb, conv_tan_b,
                                                bn1_gamma, bn1_beta, bn1_mean, bn1_var,
                                                v_w, e_part);
    k_softmax<<<B, 256, 0, stream>>>(e_part, h_mask, w_mask, v_b, out_alpha);
    k_ct<<<dim3(64, B), 256, 0, stream>>>(out_alpha, imgT, ct);
    k_g2<<<280, 256, 0, stream>>>(st1, input_y, emb_table, gru2_wh, emb2_w, gh2,
                                  ct, gru2_wi, wc_w, gi2p);
    k_fc2c<<<8, 256, 0, stream>>>(gi2p, gh2, st1, gru2_bi, gru2_bh,
                                  fc2_w, fc2_b, emb2_b, wc_b, out_hidden, pre);
    k_logits<<<(V + 63)/64, 256, 0, stream>>>(pre, out_w, out_b, out_logits);
    k_lsm<<<B, 1024, 0, stream>>>(out_logits);
}

// Round 7
// 577.666 us; speedup vs baseline: 1.1443x; 1.1443x over previous
//
#include <hip/hip_runtime.h>
#include <hip/hip_bf16.h>

// Problem constants
#define B   16
#define H   24
#define W   96
#define C   1024
#define HID 256
#define V   5000
#define EMB 256
#define HW  (H*W)          // 2304
#define BN_EPS 1e-5f
#define H2  (H+2)          // 26 (halo-padded)
#define W2  (W+2)          // 98

// d_out layout (floats): output[B*V] | hidden[B*HID] | alpha[B*HW] | att_sum[B*HW]
#define OUT0 0
#define OUT1 (B*V)
#define OUT2 (OUT1 + B*HID)
#define OUT3 (OUT2 + B*HW)

// ws layout (bytes, 256-aligned)
#define WSB_IMGT  0                      // B*HW*C bf16      = 75,497,472
#define WSB_ETP   75497472               // B*H2*W2*256 bf16 = 20,873,216
#define WSB_WTB   96370688               // 9*256*256 bf16   =  1,179,648
#define WSB_UAT   97550336               // 256*1024 bf16    =    524,288
#define WSB_E     98074624               // 2*B*HW f32       =    294,912
#define WSB_ST1   98369536               // B*256 f32
#define WSB_CT    98385920               // B*1024 f32
#define WSB_PRE   98451456               // B*128 f32
#define WSB_GIGH1 98459648               // B*1536 f32
#define WSB_GH2   98574336               // B*896 f32
#define WSB_GI2   98631680               // 4*B*896 f32

typedef __attribute__((ext_vector_type(8))) short short8;
typedef __attribute__((ext_vector_type(4))) float f32x4;

__device__ inline unsigned short f2bf(float f) {
    union { float f; unsigned int u; } v; v.f = f;
    unsigned int r = v.u + 0x7fffu + ((v.u >> 16) & 1u);   // RNE
    return (unsigned short)(r >> 16);
}
__device__ inline float bf2f(unsigned short u) {
    union { unsigned int u; float f; } v; v.u = ((unsigned int)u) << 16;
    return v.f;
}

// async global(16B) -> LDS, no VGPR round-trip. LDS dest must be wave-uniform
// base; HW scatters lane i to base + i*16 (m104).
__device__ inline void gload_lds16(const unsigned short* g, unsigned short* l) {
    __builtin_amdgcn_global_load_lds(
        (const __attribute__((address_space(1))) void*)g,
        (__attribute__((address_space(3))) void*)l,
        16, 0, 0);
}

// ---------------- img fp32 [b][c][hw] -> bf16 [b][hw][c] (gather transpose, swizzled LDS) ----------------
__global__ __launch_bounds__(256) void k_imgT(const float* img, unsigned short* imgT)
{
    int hw0 = blockIdx.x*64, c0 = blockIdx.y*128, b = blockIdx.z;
    int t = threadIdx.x;
    __shared__ __align__(16) unsigned short tr[64*256];     // 32 KB
    int row = t & 63;
    int sgb = t >> 6;                                       // 0..3 (wave-uniform)
    const float* src = img + ((size_t)b*C + c0)*HW + hw0 + row;
    #pragma unroll
    for (int k = 0; k < 4; ++k) {
        int sg = sgb + k*4;                                 // 16B slot (8 channels)
        union { short8 v; unsigned short u[8]; } pk;
        #pragma unroll
        for (int j = 0; j < 8; ++j)
            pk.u[j] = f2bf(src[(size_t)(sg*8 + j)*HW]);
        *(short8*)&tr[row*256 + (sg ^ (row & 31))*8] = pk.v;
    }
    __syncthreads();
    #pragma unroll
    for (int k = 0; k < 4; ++k) {
        int i = k*256 + t;
        int orow = i >> 4, sg = i & 15;
        *(short8*)&imgT[((size_t)(b*HW) + hw0 + orow)*1024 + c0 + sg*8] =
            *(const short8*)&tr[orow*256 + (sg ^ (orow & 31))*8];
    }
}

// ---------------- k_prep: fused wtb-repack | uat-repack | attsum-conv | ct-zero | et_p halo-zero ----------------
// B matrices repacked GRANULE-MAJOR so MFMA B-loads coalesce (16 lanes x 16B contiguous):
//   uat: [g=c/8][n=0..255][8ch]   wtb: [khw][g=c/8][n=0..255][8ch]
__global__ __launch_bounds__(256) void k_prep(
    const float* conv_w_src, unsigned short* wtb,
    const float* ua_w, unsigned short* uat,
    const float* att_in, const float* alpha_t, const float* cw, const float* cb, float* att_out,
    float* ct, unsigned short* et_p)
{
    int x = blockIdx.x, t = threadIdx.x;
    if (x < 2304) {
        int idx = x*256 + t;                                // 9*256*256
        int c = idx & 255; int o = (idx >> 8) & 255; int khw = idx >> 16;
        wtb[(((size_t)khw*32 + (c >> 3))*256 + o)*8 + (c & 7)] =
            f2bf(conv_w_src[(o*256 + c)*9 + khw]);
    } else if (x < 3328) {
        int idx = (x - 2304)*256 + t;                       // 256*1024
        int c = idx & 1023; int d = idx >> 10;
        uat[((size_t)(c >> 3)*256 + d)*8 + (c & 7)] = f2bf(ua_w[c*256 + d]);
    } else if (x < 3472) {
        int i = (x - 3328)*256 + t;                         // B*HW
        int w = i % W; int h = (i / W) % H; int b = i / HW;
        float s = cb[0];
        #pragma unroll
        for (int kh = 0; kh < 3; ++kh) {
            int r = h + kh - 1; if (r < 0 || r >= H) continue;
            #pragma unroll
            for (int kw = 0; kw < 3; ++kw) {
                int c = w + kw - 1; if (c < 0 || c >= W) continue;
                s += alpha_t[(b*H + r)*W + c]*cw[kh*3+kw];
            }
        }
        att_out[i] = att_in[i] + s;
    } else if (x < 3536) {
        ct[(x - 3472)*256 + t] = 0.f;                       // B*C
    } else {
        // halo zero: 7808 int4 per b (row0: 3136, row25: 3136, side cols: 1536)
        int flat = (x - 3536)*256 + t;                      // < 124928
        int b = flat / 7808; int r = flat - b*7808;
        int h2, w2, j;
        if (r < 3136)      { h2 = 0;  w2 = r >> 5;          j = r & 31; }
        else if (r < 6272) { h2 = 25; w2 = (r - 3136) >> 5; j = (r - 3136) & 31; }
        else {
            int rr = r - 6272;                              // < 1536
            h2 = 1 + (rr >> 6);
            int s = rr & 63;
            w2 = (s < 32) ? 0 : 97;
            j = s & 31;
        }
        ((int4*)et_p)[((size_t)(b*H2 + h2)*W2 + w2)*32 + j] = make_int4(0,0,0,0);
    }
}

// ---------------- GRU1 matmuls: gigh[b][0:768]=emb@wi, [768:1536]=h0@wh ----------------
__global__ __launch_bounds__(256) void k_tail1(
    const int* y, const float* emb_table, const float* h0,
    const float* wi, const float* wh, float* gigh)
{
    int virt = blockIdx.x*16;            // 0..1535
    int t = threadIdx.x;
    bool gi_mode = virt < 768;
    __shared__ float a_l[16*256];
    for (int i = t; i < 4096; i += 256) {
        int b = i >> 8, k = i & 255;
        a_l[i] = gi_mode ? emb_table[y[b]*EMB + k] : h0[b*HID + k];
    }
    __syncthreads();
    int nl = t & 15, b = t >> 4;
    int n = (gi_mode ? virt : virt - 768) + nl;
    const float* wp = gi_mode ? wi : wh;
    float acc = 0.f;
    #pragma unroll 16
    for (int k = 0; k < 256; ++k) acc += a_l[b*256 + k]*wp[k*768 + n];
    gigh[b*1536 + virt + nl] = acc;
}

// ---------------- k_fc1c: GRU1 nonlinearity (in-block) + fc1 -> st1 ----------------
__global__ __launch_bounds__(256) void k_fc1c(
    const float* gigh, const float* h0, const float* bi, const float* bh,
    const float* fc1_w, const float* fc1_b, float* st1)
{
    int n0 = blockIdx.x*16, t = threadIdx.x;
    __shared__ float a_l[16*256];
    for (int i = t; i < 4096; i += 256) {
        int b = i >> 8, k = i & 255;
        const float* g = gigh + b*1536;
        float ir = g[k] + bi[k], iz = g[256+k] + bi[256+k], in_ = g[512+k] + bi[512+k];
        float hr = g[768+k] + bh[k], hz = g[1024+k] + bh[256+k], hn = g[1280+k] + bh[512+k];
        float r = 1.f/(1.f+__expf(-(ir+hr)));
        float z = 1.f/(1.f+__expf(-(iz+hz)));
        float n = tanhf(in_ + r*hn);
        a_l[i] = (1.f - z)*n + z*h0[b*HID + k];
    }
    __syncthreads();
    int nl = t & 15, b = t >> 4;
    float acc = fc1_b[n0+nl];
    #pragma unroll 16
    for (int k = 0; k < 256; ++k) acc += a_l[b*256+k]*fc1_w[k*256 + n0 + nl];
    st1[b*256 + n0 + nl] = acc;
}

// ---------------- K4: MFMA GEMM et = imgT @ ua_w + epilogue -> bf16 NHWC halo-padded ----------------
// 48 rows/block, grid 1536 = 6/CU. Waves 1m x 4n. A: async gload_lds dbuf, linear
// dest + pre-swizzled source; read granule q^(m&7), addr folds to ebase ^ cs (free).
// B (uat) now granule-major: quarter-wave reads 256B contiguous (was 16 scattered
// lines/instr -> TA-bound, the r6 occupancy-insensitive ceiling).
__global__ __launch_bounds__(256, 6) void k_et(
    const unsigned short* imgT, const unsigned short* uat, const float* ua_b,
    const float* st1, const float* att_sum, const float* uf_w, const float* uf_b,
    unsigned short* et_p)
{
    int hb = blockIdx.x; int h = hb >> 1, mh = hb & 1;
    int ny = blockIdx.y, b = blockIdx.z;
    int t = threadIdx.x;
    int wv = t >> 6, lane = t & 63, q = lane >> 4, ln = lane & 15;
    int n0 = ny*128 + wv*32;
    __shared__ __align__(16) unsigned short a_l[2*6144];    // 2 x 12.3 KB

    f32x4 acc[6];                                           // [mf*2 + j]
    #pragma unroll
    for (int i = 0; i < 6; ++i) acc[i] = (f32x4){0.f,0.f,0.f,0.f};

    const unsigned short* ab = imgT + ((size_t)(b*HW) + h*W + mh*48)*1024;
    // repacked uat: [g][n][8]; per-lane base (granule q, column n0+ln)
    const unsigned short* ub = uat + (size_t)q*2048 + (size_t)(n0 + ln)*8;

    int ebase[3];
    #pragma unroll
    for (int mf = 0; mf < 3; ++mf) {
        int m = ln + 16*mf;
        ebase[mf] = m*128 + (q ^ (m & 7))*8;
    }

    // staging: 768 slots/chunk, 12 issues; wave wv does g = wv + 4*it (it 0..2)
    int goff[3], loff[3];
    #pragma unroll
    for (int it = 0; it < 3; ++it) {
        int g = wv + it*4;
        int L = g*64 + lane;                                // 0..767
        int m = L >> 4, s = L & 15;
        int sig = (s & 8) | ((s ^ m) & 7);
        goff[it] = m*1024 + sig*8;
        loff[it] = g*512;                                   // shorts, wave-uniform
    }

    #pragma unroll
    for (int it = 0; it < 3; ++it)
        gload_lds16(ab + goff[it], &a_l[loff[it]]);
    __syncthreads();

    int cur = 0;
    for (int c0 = 0; c0 < 1024; c0 += 128) {
        int bufS = cur*6144, nbufS = bufS ^ 6144;
        if (c0 < 896) {
            #pragma unroll
            for (int it = 0; it < 3; ++it)
                gload_lds16(ab + goff[it] + c0 + 128, &a_l[nbufS + loff[it]]);
        }
        #pragma unroll
        for (int cs = 0; cs < 128; cs += 32) {
            short8 av[3];
            #pragma unroll
            for (int mf = 0; mf < 3; ++mf)
                av[mf] = *(const short8*)&a_l[bufS + (ebase[mf] ^ cs)];
            const unsigned short* bp = ub + (size_t)((c0 + cs) >> 3)*2048;
            #pragma unroll
            for (int j = 0; j < 2; ++j) {
                short8 bv = *(const short8*)(bp + j*128);
                #pragma unroll
                for (int mf = 0; mf < 3; ++mf)
                    acc[mf*2+j] = __builtin_amdgcn_mfma_f32_16x16x32_bf16(av[mf], bv, acc[mf*2+j], 0, 0, 0);
            }
        }
        __syncthreads();                                    // drains vmcnt + barrier
        cur ^= 1;
    }

    float att_m[12];
    #pragma unroll
    for (int mf = 0; mf < 3; ++mf)
        #pragma unroll
        for (int r = 0; r < 4; ++r)
            att_m[mf*4+r] = att_sum[(b*H + h)*W + mh*48 + mf*16 + q*4 + r];
    #pragma unroll
    for (int j = 0; j < 2; ++j) {
        int n = n0 + j*16 + ln;
        float s1 = st1[b*256 + n] + ua_b[n];
        float ufw = uf_w[n], ufb = uf_b[n];
        #pragma unroll
        for (int mf = 0; mf < 3; ++mf)
            #pragma unroll
            for (int r = 0; r < 4; ++r) {
                int m = mh*48 + mf*16 + q*4 + r;
                float v = acc[mf*2+j][r] + s1 + att_m[mf*4+r]*ufw + ufb;
                et_p[((size_t)(b*H2 + h + 1)*W2 + (m + 1))*256 + n] = f2bf(v);
            }
    }
}

// ---------------- K5: MFMA conv(3x3,256->256) + BN + tanh + v-dot -> e_part[ny][b,h,w] ----------------
// 48 cols/block (+2 halo), grid 1536 = 6/CU. Patch dbuf 2x9.6 KB. Swizzle fixed back
// to ((x2>>1)&3) (r6's (x2&3) was 4-way, conflicts 5.3M). B (wtb) granule-major:
// quarter-wave reads 256B contiguous.
__global__ __launch_bounds__(256, 6) void k_conv(
    const unsigned short* et_p, const unsigned short* wtb, const float* cb,
    const float* bn_g, const float* bn_b, const float* bn_m, const float* bn_v,
    const float* v_w, float* e_part)
{
    int hb = blockIdx.x; int h = hb >> 1, mh = hb & 1;
    int ny = blockIdx.y, b = blockIdx.z;
    int t = threadIdx.x;
    int wv = t >> 6, lane = t & 63, q = lane >> 4, ln = lane & 15;
    int n0 = ny*128 + wv*32;
    __shared__ __align__(16) unsigned short patch[2*4800];  // 2 x 9.6 KB
    __shared__ float lds_red[4][48];

    f32x4 acc[6];                                           // [mf*2 + j]
    #pragma unroll
    for (int i = 0; i < 6; ++i) acc[i] = (f32x4){0.f,0.f,0.f,0.f};

    int abase[3][3];                                        // shorts, within plane (stride 1600)
    #pragma unroll
    for (int mf = 0; mf < 3; ++mf)
        #pragma unroll
        for (int kw = 0; kw < 3; ++kw) {
            int x2 = ln + 16*mf + kw;                       // 0..49 local
            abase[mf][kw] = x2*32 + (q ^ ((x2 >> 1) & 3))*8;
        }

    const unsigned short* gb = et_p + ((size_t)(b*H2 + h)*W2 + mh*48)*256;
    // repacked wtb: [khw][g][n][8]; per-lane base (granule q, column n0+ln)
    const unsigned short* wb = wtb + (size_t)q*2048 + (size_t)(n0 + ln)*8;

    // staging: 600 slots/chunk (3 x 50 x 4), 10 issues; wave wv: g = wv + 4*it;
    // g=9 partial (24 lanes); waves 2,3 skip it=2.
    int goff[3], loff[3]; bool la[3];
    #pragma unroll
    for (int it = 0; it < 3; ++it) {
        int g = wv + it*4;
        int L = g*64 + lane;
        la[it] = (g < 10) && (L < 600);
        int Lc = la[it] ? L : 0;
        int pl = Lc / 200; int rem = Lc - pl*200;
        int x2 = rem >> 2, s = rem & 3;
        goff[it] = (pl*W2 + x2)*256 + (s ^ ((x2 >> 1) & 3))*8;
        loff[it] = g*512;                                   // shorts, wave-uniform
    }

    #pragma unroll
    for (int it = 0; it < 3; ++it)
        if (la[it]) gload_lds16(gb + goff[it], &patch[loff[it]]);
    __syncthreads();

    int cur = 0;
    for (int cc = 0; cc < 8; ++cc) {
        int bufS = cur*4800, nbufS = bufS ^ 4800;
        if (cc < 7) {
            int c1 = (cc + 1)*32;
            #pragma unroll
            for (int it = 0; it < 3; ++it)
                if (la[it]) gload_lds16(gb + goff[it] + c1, &patch[nbufS + loff[it]]);
        }
        #pragma unroll
        for (int kh = 0; kh < 3; ++kh) {
            #pragma unroll
            for (int kw = 0; kw < 3; ++kw) {
                short8 av[3];
                #pragma unroll
                for (int mf = 0; mf < 3; ++mf)
                    av[mf] = *(const short8*)&patch[bufS + kh*1600 + abase[mf][kw]];
                const unsigned short* bp = wb + (size_t)(kh*3 + kw)*65536 + (size_t)cc*8192;
                #pragma unroll
                for (int j = 0; j < 2; ++j) {
                    short8 bv = *(const short8*)(bp + j*128);
                    #pragma unroll
                    for (int mf = 0; mf < 3; ++mf)
                        acc[mf*2+j] = __builtin_amdgcn_mfma_f32_16x16x32_bf16(av[mf], bv, acc[mf*2+j], 0, 0, 0);
                }
            }
        }
        __syncthreads();                                    // drains vmcnt + barrier
        cur ^= 1;
    }

    float psum[12];
    #pragma unroll
    for (int i = 0; i < 12; ++i) psum[i] = 0.f;
    #pragma unroll
    for (int j = 0; j < 2; ++j) {
        int o = n0 + j*16 + ln;
        float inv  = bn_g[o]*rsqrtf(bn_v[o] + BN_EPS);
        float mean = bn_m[o], beta = bn_b[o], bias = cb[o], vw = v_w[o];
        #pragma unroll
        for (int mf = 0; mf < 3; ++mf)
            #pragma unroll
            for (int r = 0; r < 4; ++r) {
                float x = (acc[mf*2+j][r] + bias - mean)*inv + beta;
                x = fminf(fmaxf(x, -15.f), 15.f);
                float ex = __expf(2.f*x);
                psum[mf*4+r] += ((ex - 1.f)/(ex + 1.f))*vw;
            }
    }
    #pragma unroll
    for (int s = 1; s < 16; s <<= 1)
        #pragma unroll
        for (int i = 0; i < 12; ++i) psum[i] += __shfl_xor(psum[i], s);
    if (ln == 0) {
        #pragma unroll
        for (int mf = 0; mf < 3; ++mf)
            #pragma unroll
            for (int r = 0; r < 4; ++r)
                lds_red[wv][mf*16 + q*4 + r] = psum[mf*4+r];
    }
    __syncthreads();
    if (t < 48)
        e_part[(size_t)ny*(B*HW) + (b*H + h)*W + mh*48 + t] =
            lds_red[0][t] + lds_red[1][t] + lds_red[2][t] + lds_red[3][t];
}

// ---------------- K6: masked softmax over (h,w) -> alpha (sums the two e partials) ----------------
__global__ __launch_bounds__(256) void k_softmax(
    const float* e_part, const int* h_mask, const int* w_mask, const float* v_b,
    float* alpha_out)
{
    int b = blockIdx.x, t = threadIdx.x;
    int hm = h_mask[b], wm = w_mask[b];
    float vb = v_b[0];
    __shared__ float red[256];
    float vals[9];
    float loc = 0.f;
    #pragma unroll
    for (int i = 0; i < 9; ++i) {
        int hw = t + i*256;
        int hh = hw / W, ww = hw % W;
        float v = 0.f;
        if (hh < hm && ww < wm)
            v = __expf(e_part[b*HW + hw] + e_part[B*HW + b*HW + hw] + vb);
        vals[i] = v; loc += v;
    }
    red[t] = loc; __syncthreads();
    for (int s = 128; s > 0; s >>= 1) { if (t < s) red[t] += red[t+s]; __syncthreads(); }
    float inv = 1.f/(red[0] + 1e-8f);
    #pragma unroll
    for (int i = 0; i < 9; ++i) alpha_out[b*HW + t + i*256] = vals[i]*inv;
}

// ---------------- K7: ct[b,c] += sum_hw alpha[b,hw]*imgT[b,hw,c] (bf16 A, fp32 acc, atomics) ----------------
__global__ __launch_bounds__(256) void k_ct(
    const float* alpha, const unsigned short* imgT, float* ct)
{
    int s = blockIdx.x, b = blockIdx.y, t = threadIdx.x;
    int cg = (t & 127)*8, half = t >> 7;
    float acc[8];
    #pragma unroll
    for (int j = 0; j < 8; ++j) acc[j] = 0.f;
    for (int i = 0; i < 18; ++i) {
        int hw = s*36 + i*2 + half;
        float a = alpha[b*HW + hw];
        union { short8 v; unsigned short u[8]; } pk;
        pk.v = *(const short8*)&imgT[((size_t)(b*HW) + hw)*1024 + cg];
        #pragma unroll
        for (int j = 0; j < 8; ++j) acc[j] += a*bf2f(pk.u[j]);
    }
    #pragma unroll
    for (int j = 0; j < 8; ++j) atomicAdd(&ct[b*1024 + cg + j], acc[j]);
}

// ---------------- k_g2: fused GRU2 h-side+pemb | GRU2 i-side+wc (split-K) ----------------
__global__ __launch_bounds__(256) void k_g2(
    const float* st1, const int* y, const float* emb_table,
    const float* wh, const float* emb2_w, float* gh2,
    const float* ct, const float* wi, const float* wc_w, float* gi2p)
{
    int x = blockIdx.x, t = threadIdx.x;
    __shared__ float a_l[16*256];
    if (x < 56) {
        int virt = x*16;
        bool ghm = virt < 768;
        for (int i = t; i < 4096; i += 256) {
            int b = i >> 8, k = i & 255;
            a_l[i] = ghm ? st1[b*256 + k] : emb_table[y[b]*EMB + k];
        }
        __syncthreads();
        int nl = t & 15, b = t >> 4;
        float acc = 0.f;
        if (ghm) {
            int n = virt + nl;
            #pragma unroll 16
            for (int k = 0; k < 256; ++k) acc += a_l[b*256+k]*wh[k*768 + n];
        } else {
            int n = virt - 768 + nl;
            #pragma unroll 16
            for (int k = 0; k < 256; ++k) acc += a_l[b*256+k]*emb2_w[k*128 + n];
        }
        gh2[b*896 + virt + nl] = acc;
    } else {
        int xx = x - 56;
        int ks = xx / 56, virt = (xx - ks*56)*16;
        int k0 = ks*256;
        for (int i = t; i < 4096; i += 256) {
            int b = i >> 8, k = i & 255;
            a_l[i] = ct[b*1024 + k0 + k];
        }
        __syncthreads();
        int nl = t & 15, b = t >> 4;
        float acc = 0.f;
        if (virt < 768) {
            int n = virt + nl;
            #pragma unroll 16
            for (int k = 0; k < 256; ++k) acc += a_l[b*256+k]*wi[(k0+k)*768 + n];
        } else {
            int n = virt - 768 + nl;
            #pragma unroll 16
            for (int k = 0; k < 256; ++k) acc += a_l[b*256+k]*wc_w[(k0+k)*128 + n];
        }
        gi2p[(ks*16 + b)*896 + virt + nl] = acc;
    }
}

// ---------------- k_fc2c: GRU2 nonlinearity (in-block) + hidden write + pre ----------------
__global__ __launch_bounds__(256) void k_fc2c(
    const float* gi2p, const float* gh2, const float* st1,
    const float* bi, const float* bh,
    const float* fc2_w, const float* fc2_b, const float* emb2_b, const float* wc_b,
    float* hidden_out, float* pre)
{
    int n0 = blockIdx.x*16, t = threadIdx.x;
    __shared__ float st_l[16*256];
    for (int i = t; i < 4096; i += 256) {
        int b = i >> 8, k = i & 255;
        float ir = bi[k], iz = bi[256+k], in_ = bi[512+k];
        #pragma unroll
        for (int ks = 0; ks < 4; ++ks) {
            const float* g = gi2p + (ks*16 + b)*896;
            ir += g[k]; iz += g[256+k]; in_ += g[512+k];
        }
        const float* gh = gh2 + b*896;
        float hr = gh[k] + bh[k], hz = gh[256+k] + bh[256+k], hn = gh[512+k] + bh[512+k];
        float h = st1[b*256+k];
        float r = 1.f/(1.f+__expf(-(ir+hr)));
        float z = 1.f/(1.f+__expf(-(iz+hz)));
        float n = tanhf(in_ + r*hn);
        float s = (1.f - z)*n + z*h;
        st_l[i] = s;
        if (blockIdx.x == 0) hidden_out[b*HID + k] = s;
    }
    __syncthreads();
    int nl = t & 15, b = t >> 4;
    int n = n0 + nl;
    float acc = fc2_b[n] + emb2_b[n] + wc_b[n] + gh2[b*896 + 768 + n];
    #pragma unroll
    for (int ks = 0; ks < 4; ++ks) acc += gi2p[(ks*16 + b)*896 + 768 + n];
    #pragma unroll 16
    for (int k = 0; k < 256; ++k) acc += st_l[b*256+k]*fc2_w[k*128 + n];
    pre[b*128 + n] = acc;
}

// ---------------- logits (raw) = pre @ out_w + out_b ----------------
__global__ __launch_bounds__(256) void k_logits(
    const float* pre, const float* out_w, const float* out_b, float* out)
{
    int j0 = blockIdx.x*64, t = threadIdx.x;
    __shared__ float pre_l[16*128];
    for (int i = t; i < 2048; i += 256) pre_l[i] = pre[i];
    __syncthreads();
    int jl = t & 63, bg = t >> 6;
    int j = j0 + jl;
    if (j >= V) return;
    float acc0=0.f, acc1=0.f, acc2=0.f, acc3=0.f;
    const float* pl = pre_l + bg*4*128;
    #pragma unroll 8
    for (int k = 0; k < 128; ++k) {
        float wv = out_w[k*V + j];
        acc0 += pl[k]*wv; acc1 += pl[128+k]*wv; acc2 += pl[256+k]*wv; acc3 += pl[384+k]*wv;
    }
    float ob = out_b[j];
    out[(bg*4+0)*V + j] = acc0 + ob;
    out[(bg*4+1)*V + j] = acc1 + ob;
    out[(bg*4+2)*V + j] = acc2 + ob;
    out[(bg*4+3)*V + j] = acc3 + ob;
}

// ---------------- in-place log_softmax over V per batch ----------------
__global__ __launch_bounds__(1024) void k_lsm(float* out)
{
    int b = blockIdx.x, t = threadIdx.x;
    __shared__ float red[1024];
    float lg[5]; float mx = -1e30f;
    #pragma unroll
    for (int i = 0; i < 5; ++i) {
        int j = t + i*1024;
        lg[i] = (j < V) ? out[b*V + j] : -1e30f;
        mx = fmaxf(mx, lg[i]);
    }
    red[t] = mx; __syncthreads();
    for (int s = 512; s > 0; s >>= 1) { if (t < s) red[t] = fmaxf(red[t], red[t+s]); __syncthreads(); }
    float gmax = red[0]; __syncthreads();
    float se = 0.f;
    #pragma unroll
    for (int i = 0; i < 5; ++i) { int j = t + i*1024; if (j < V) se += __expf(lg[i] - gmax); }
    red[t] = se; __syncthreads();
    for (int s = 512; s > 0; s >>= 1) { if (t < s) red[t] += red[t+s]; __syncthreads(); }
    float lse = logf(red[0]);
    #pragma unroll
    for (int i = 0; i < 5; ++i) { int j = t + i*1024; if (j < V) out[b*V + j] = lg[i] - gmax - lse; }
}

extern "C" void kernel_launch(void* const* d_in, const int* in_sizes, int n_in,
                              void* d_out, int out_size, void* d_ws, size_t ws_size,
                              hipStream_t stream)
{
    const int*   input_y      = (const int*)  d_in[0];
    const float* input_hidden = (const float*)d_in[1];
    const float* img          = (const float*)d_in[2];
    const float* attention    = (const float*)d_in[4];
    const float* alpha_t      = (const float*)d_in[5];
    const int*   h_mask       = (const int*)  d_in[8];
    const int*   w_mask       = (const int*)  d_in[9];
    const float* emb_table    = (const float*)d_in[10];
    const float* gru1_wi      = (const float*)d_in[11];
    const float* gru1_wh      = (const float*)d_in[12];
    const float* gru1_bi      = (const float*)d_in[13];
    const float* gru1_bh      = (const float*)d_in[14];
    const float* fc1_w        = (const float*)d_in[15];
    const float* fc1_b        = (const float*)d_in[16];
    const float* gru2_wi      = (const float*)d_in[17];
    const float* gru2_wh      = (const float*)d_in[18];
    const float* gru2_bi      = (const float*)d_in[19];
    const float* gru2_bh      = (const float*)d_in[20];
    const float* out_w        = (const float*)d_in[21];
    const float* out_b        = (const float*)d_in[22];
    const float* emb2_w       = (const float*)d_in[23];
    const float* emb2_b       = (const float*)d_in[24];
    const float* conv1_w      = (const float*)d_in[25];
    const float* conv1_b      = (const float*)d_in[26];
    const float* conv_tan_w   = (const float*)d_in[27];
    const float* conv_tan_b   = (const float*)d_in[28];
    const float* fc2_w        = (const float*)d_in[29];
    const float* fc2_b        = (const float*)d_in[30];
    const float* ua_w         = (const float*)d_in[31];
    const float* ua_b         = (const float*)d_in[32];
    const float* uf_w         = (const float*)d_in[33];
    const float* uf_b         = (const float*)d_in[34];
    const float* v_w          = (const float*)d_in[35];
    const float* v_b          = (const float*)d_in[36];
    const float* wc_w         = (const float*)d_in[37];
    const float* wc_b         = (const float*)d_in[38];
    const float* bn1_gamma    = (const float*)d_in[39];
    const float* bn1_beta     = (const float*)d_in[40];
    const float* bn1_mean     = (const float*)d_in[41];
    const float* bn1_var      = (const float*)d_in[42];

    float* out = (float*)d_out;
    char*  ws  = (char*)d_ws;
    unsigned short* imgT = (unsigned short*)(ws + WSB_IMGT);
    unsigned short* et_p = (unsigned short*)(ws + WSB_ETP);
    unsigned short* wtb  = (unsigned short*)(ws + WSB_WTB);
    unsigned short* uat  = (unsigned short*)(ws + WSB_UAT);
    float* e_part = (float*)(ws + WSB_E);
    float* st1   = (float*)(ws + WSB_ST1);
    float* ct    = (float*)(ws + WSB_CT);
    float* pre   = (float*)(ws + WSB_PRE);
    float* gigh1 = (float*)(ws + WSB_GIGH1);
    float* gh2   = (float*)(ws + WSB_GH2);
    float* gi2p  = (float*)(ws + WSB_GI2);

    float* out_logits = out + OUT0;
    float* out_hidden = out + OUT1;
    float* out_alpha  = out + OUT2;
    float* out_attsum = out + OUT3;

    k_imgT<<<dim3(HW/64, C/128, B), 256, 0, stream>>>(img, imgT);
    k_prep<<<4024, 256, 0, stream>>>(conv_tan_w, wtb, ua_w, uat,
                                     attention, alpha_t, conv1_w, conv1_b, out_attsum,
                                     ct, et_p);
    k_tail1<<<96, 256, 0, stream>>>(input_y, emb_table, input_hidden,
                                    gru1_wi, gru1_wh, gigh1);
    k_fc1c<<<16, 256, 0, stream>>>(gigh1, input_hidden, gru1_bi, gru1_bh,
                                   fc1_w, fc1_b, st1);
    k_et<<<dim3(H*2, 2, B), 256, 0, stream>>>(imgT, uat, ua_b, st1, out_attsum,
                                              uf_w, uf_b, et_p);
    k_conv<<<dim3(H*2, 2, B), 256, 0, stream>>>(et_p, wtb, conv_tan_b,
                                                bn1_gamma, bn1_beta, bn1_mean, bn1_var,
                                                v_w, e_part);
    k_softmax<<<B, 256, 0, stream>>>(e_part, h_mask, w_mask, v_b, out_alpha);
    k_ct<<<dim3(64, B), 256, 0, stream>>>(out_alpha, imgT, ct);
    k_g2<<<280, 256, 0, stream>>>(st1, input_y, emb_table, gru2_wh, emb2_w, gh2,
                                  ct, gru2_wi, wc_w, gi2p);
    k_fc2c<<<8, 256, 0, stream>>>(gi2p, gh2, st1, gru2_bi, gru2_bh,
                                  fc2_w, fc2_b, emb2_b, wc_b, out_hidden, pre);
    k_logits<<<(V + 63)/64, 256, 0, stream>>>(pre, out_w, out_b, out_logits);
    k_lsm<<<B, 1024, 0, stream>>>(out_logits);
}

// Round 8
// 534.204 us; speedup vs baseline: 1.2374x; 1.0814x over previous
//
#include <hip/hip_runtime.h>
#include <hip/hip_bf16.h>

// Problem constants
#define B   16
#define H   24
#define W   96
#define C   1024
#define HID 256
#define V   5000
#define EMB 256
#define HW  (H*W)          // 2304
#define BN_EPS 1e-5f
#define H2  (H+2)          // 26 (halo-padded)
#define W2  (W+2)          // 98

// d_out layout (floats): output[B*V] | hidden[B*HID] | alpha[B*HW] | att_sum[B*HW]
#define OUT0 0
#define OUT1 (B*V)
#define OUT2 (OUT1 + B*HID)
#define OUT3 (OUT2 + B*HW)

// ws layout (bytes, 256-aligned)
#define WSB_IMGT  0                      // B*HW*C bf16      = 75,497,472
#define WSB_ETP   75497472               // B*H2*W2*256 bf16 = 20,873,216
#define WSB_WTB   96370688               // 9*256*256 bf16   =  1,179,648
#define WSB_UAT   97550336               // 256*1024 bf16    =    524,288
#define WSB_E     98074624               // 2*B*HW f32       =    294,912
#define WSB_ST1   98369536               // B*256 f32
#define WSB_CT    98385920               // B*1024 f32
#define WSB_PRE   98451456               // B*128 f32
#define WSB_GIGH1 98459648               // B*1536 f32
#define WSB_GH2   98574336               // B*896 f32
#define WSB_GI2   98631680               // 4*B*896 f32

typedef __attribute__((ext_vector_type(8))) short short8;
typedef __attribute__((ext_vector_type(4))) float f32x4;

__device__ inline unsigned short f2bf(float f) {
    union { float f; unsigned int u; } v; v.f = f;
    unsigned int r = v.u + 0x7fffu + ((v.u >> 16) & 1u);   // RNE
    return (unsigned short)(r >> 16);
}
__device__ inline float bf2f(unsigned short u) {
    union { unsigned int u; float f; } v; v.u = ((unsigned int)u) << 16;
    return v.f;
}

// ---------------- img fp32 [b][c][hw] -> bf16 [b][hw][c] (gather transpose, swizzled LDS) ----------------
__global__ __launch_bounds__(256) void k_imgT(const float* img, unsigned short* imgT)
{
    int hw0 = blockIdx.x*64, c0 = blockIdx.y*128, b = blockIdx.z;
    int t = threadIdx.x;
    __shared__ __align__(16) unsigned short tr[64*256];     // 32 KB
    int row = t & 63;
    int sgb = t >> 6;                                       // 0..3 (wave-uniform)
    const float* src = img + ((size_t)b*C + c0)*HW + hw0 + row;
    #pragma unroll
    for (int k = 0; k < 4; ++k) {
        int sg = sgb + k*4;                                 // 16B slot (8 channels)
        union { short8 v; unsigned short u[8]; } pk;
        #pragma unroll
        for (int j = 0; j < 8; ++j)
            pk.u[j] = f2bf(src[(size_t)(sg*8 + j)*HW]);
        *(short8*)&tr[row*256 + (sg ^ (row & 31))*8] = pk.v;
    }
    __syncthreads();
    #pragma unroll
    for (int k = 0; k < 4; ++k) {
        int i = k*256 + t;
        int orow = i >> 4, sg = i & 15;
        *(short8*)&imgT[((size_t)(b*HW) + hw0 + orow)*1024 + c0 + sg*8] =
            *(const short8*)&tr[orow*256 + (sg ^ (orow & 31))*8];
    }
}

// ---------------- k_prep: fused wtb-repack | uat-repack | attsum-conv | ct-zero | et_p halo-zero ----------------
// B matrices GRANULE-MAJOR so MFMA B-loads coalesce (16 lanes x 16B contiguous):
//   uat: [g=c/8][n=0..255][8ch]   wtb: [khw][g=c/8][n=0..255][8ch]  (r7-verified win)
__global__ __launch_bounds__(256) void k_prep(
    const float* conv_w_src, unsigned short* wtb,
    const float* ua_w, unsigned short* uat,
    const float* att_in, const float* alpha_t, const float* cw, const float* cb, float* att_out,
    float* ct, unsigned short* et_p)
{
    int x = blockIdx.x, t = threadIdx.x;
    if (x < 2304) {
        int idx = x*256 + t;                                // 9*256*256
        int c = idx & 255; int o = (idx >> 8) & 255; int khw = idx >> 16;
        wtb[(((size_t)khw*32 + (c >> 3))*256 + o)*8 + (c & 7)] =
            f2bf(conv_w_src[(o*256 + c)*9 + khw]);
    } else if (x < 3328) {
        int idx = (x - 2304)*256 + t;                       // 256*1024
        int c = idx & 1023; int d = idx >> 10;
        uat[((size_t)(c >> 3)*256 + d)*8 + (c & 7)] = f2bf(ua_w[c*256 + d]);
    } else if (x < 3472) {
        int i = (x - 3328)*256 + t;                         // B*HW
        int w = i % W; int h = (i / W) % H; int b = i / HW;
        float s = cb[0];
        #pragma unroll
        for (int kh = 0; kh < 3; ++kh) {
            int r = h + kh - 1; if (r < 0 || r >= H) continue;
            #pragma unroll
            for (int kw = 0; kw < 3; ++kw) {
                int c = w + kw - 1; if (c < 0 || c >= W) continue;
                s += alpha_t[(b*H + r)*W + c]*cw[kh*3+kw];
            }
        }
        att_out[i] = att_in[i] + s;
    } else if (x < 3536) {
        ct[(x - 3472)*256 + t] = 0.f;                       // B*C
    } else {
        // halo zero: 7808 int4 per b (row0: 3136, row25: 3136, side cols: 1536)
        int flat = (x - 3536)*256 + t;                      // < 124928
        int b = flat / 7808; int r = flat - b*7808;
        int h2, w2, j;
        if (r < 3136)      { h2 = 0;  w2 = r >> 5;          j = r & 31; }
        else if (r < 6272) { h2 = 25; w2 = (r - 3136) >> 5; j = (r - 3136) & 31; }
        else {
            int rr = r - 6272;                              // < 1536
            h2 = 1 + (rr >> 6);
            int s = rr & 63;
            w2 = (s < 32) ? 0 : 97;
            j = s & 31;
        }
        ((int4*)et_p)[((size_t)(b*H2 + h2)*W2 + w2)*32 + j] = make_int4(0,0,0,0);
    }
}

// ---------------- GRU1 matmuls: gigh[b][0:768]=emb@wi, [768:1536]=h0@wh ----------------
__global__ __launch_bounds__(256) void k_tail1(
    const int* y, const float* emb_table, const float* h0,
    const float* wi, const float* wh, float* gigh)
{
    int virt = blockIdx.x*16;            // 0..1535
    int t = threadIdx.x;
    bool gi_mode = virt < 768;
    __shared__ float a_l[16*256];
    for (int i = t; i < 4096; i += 256) {
        int b = i >> 8, k = i & 255;
        a_l[i] = gi_mode ? emb_table[y[b]*EMB + k] : h0[b*HID + k];
    }
    __syncthreads();
    int nl = t & 15, b = t >> 4;
    int n = (gi_mode ? virt : virt - 768) + nl;
    const float* wp = gi_mode ? wi : wh;
    float acc = 0.f;
    #pragma unroll 16
    for (int k = 0; k < 256; ++k) acc += a_l[b*256 + k]*wp[k*768 + n];
    gigh[b*1536 + virt + nl] = acc;
}

// ---------------- k_fc1c: GRU1 nonlinearity (in-block) + fc1 -> st1 ----------------
__global__ __launch_bounds__(256) void k_fc1c(
    const float* gigh, const float* h0, const float* bi, const float* bh,
    const float* fc1_w, const float* fc1_b, float* st1)
{
    int n0 = blockIdx.x*16, t = threadIdx.x;
    __shared__ float a_l[16*256];
    for (int i = t; i < 4096; i += 256) {
        int b = i >> 8, k = i & 255;
        const float* g = gigh + b*1536;
        float ir = g[k] + bi[k], iz = g[256+k] + bi[256+k], in_ = g[512+k] + bi[512+k];
        float hr = g[768+k] + bh[k], hz = g[1024+k] + bh[256+k], hn = g[1280+k] + bh[512+k];
        float r = 1.f/(1.f+__expf(-(ir+hr)));
        float z = 1.f/(1.f+__expf(-(iz+hz)));
        float n = tanhf(in_ + r*hn);
        a_l[i] = (1.f - z)*n + z*h0[b*HID + k];
    }
    __syncthreads();
    int nl = t & 15, b = t >> 4;
    float acc = fc1_b[n0+nl];
    #pragma unroll 16
    for (int k = 0; k < 256; ++k) acc += a_l[b*256+k]*fc1_w[k*256 + n0 + nl];
    st1[b*256 + n0 + nl] = acc;
}

// ---------------- K4: MFMA GEMM et = imgT @ ua_w + epilogue -> bf16 NHWC halo-padded ----------------
// r1 skeleton (4 waves x 96m x 32n, 128-c chunks, direct staging, 2 barriers/chunk)
// + fix A: tight 256B rows, phys granule s holds logical s^(m&7) -> read addr folds
//   to ebase^cs; 8 bank-groups x 2 lanes on both write and read sides (free).
// + fix B: granule-major uat -> quarter-wave reads 256B contiguous (r7-verified).
__global__ __launch_bounds__(256, 3) void k_et(
    const unsigned short* imgT, const unsigned short* uat, const float* ua_b,
    const float* st1, const float* att_sum, const float* uf_w, const float* uf_b,
    unsigned short* et_p)
{
    int h = blockIdx.x, ny = blockIdx.y, b = blockIdx.z;
    int t = threadIdx.x;
    int wv = t >> 6, lane = t & 63, q = lane >> 4, ln = lane & 15;
    int n0 = ny*128 + wv*32;
    __shared__ __align__(16) unsigned short a_l[96*128];    // 24 KB, 256B rows

    f32x4 acc[12];                                          // [mf*2 + j]
    #pragma unroll
    for (int i = 0; i < 12; ++i) acc[i] = (f32x4){0.f,0.f,0.f,0.f};

    const unsigned short* ab = imgT + ((size_t)(b*HW) + h*W)*1024;

    int ebase[6];
    #pragma unroll
    for (int mf = 0; mf < 6; ++mf) {
        int m = ln + 16*mf;
        ebase[mf] = m*128 + (q ^ (m & 7))*8;
    }

    for (int c0 = 0; c0 < 1024; c0 += 128) {
        __syncthreads();                                    // prior reads done
        #pragma unroll
        for (int k = 0; k < 6; ++k) {
            int i = t + k*256;                              // < 1536
            int m = i >> 4, s = i & 15;
            ((int4*)a_l)[m*16 + s] =
                *((const int4*)(ab + (size_t)m*1024 + c0) + (s ^ (m & 7)));
        }
        __syncthreads();                                    // writes visible
        #pragma unroll
        for (int cs = 0; cs < 128; cs += 32) {
            short8 av[6];
            #pragma unroll
            for (int mf = 0; mf < 6; ++mf)
                av[mf] = *(const short8*)&a_l[ebase[mf] ^ cs];
            const unsigned short* bp =
                uat + ((size_t)(((c0 + cs) >> 3) + q)*256 + n0 + ln)*8;
            #pragma unroll
            for (int j = 0; j < 2; ++j) {
                short8 bv = *(const short8*)(bp + j*128);
                #pragma unroll
                for (int mf = 0; mf < 6; ++mf)
                    acc[mf*2+j] = __builtin_amdgcn_mfma_f32_16x16x32_bf16(av[mf], bv, acc[mf*2+j], 0, 0, 0);
            }
        }
    }

    float att_m[24];
    #pragma unroll
    for (int mf = 0; mf < 6; ++mf)
        #pragma unroll
        for (int r = 0; r < 4; ++r)
            att_m[mf*4+r] = att_sum[(b*H + h)*W + mf*16 + q*4 + r];
    #pragma unroll
    for (int j = 0; j < 2; ++j) {
        int n = n0 + j*16 + ln;
        float s1 = st1[b*256 + n] + ua_b[n];
        float ufw = uf_w[n], ufb = uf_b[n];
        #pragma unroll
        for (int mf = 0; mf < 6; ++mf)
            #pragma unroll
            for (int r = 0; r < 4; ++r) {
                int m = mf*16 + q*4 + r;
                float v = acc[mf*2+j][r] + s1 + att_m[mf*4+r]*ufw + ufb;
                et_p[((size_t)(b*H2 + h + 1)*W2 + (m + 1))*256 + n] = f2bf(v);
            }
    }
}

// ---------------- K5: MFMA conv(3x3,256->256) + BN + tanh + v-dot -> e_part[ny][b,h,w] ----------------
// r1 skeleton (4 waves x 96m x 32n, 64-c chunks, direct staging) + fixes:
// patch tight 128B rows, phys granule s holds s^(x2&7) -> conflict-free reads
// (r3-verified swizzle family); B granule-major wtb -> coalesced (r7-verified).
__global__ __launch_bounds__(256, 3) void k_conv(
    const unsigned short* et_p, const unsigned short* wtb, const float* cb,
    const float* bn_g, const float* bn_b, const float* bn_m, const float* bn_v,
    const float* v_w, float* e_part)
{
    int h = blockIdx.x, ny = blockIdx.y, b = blockIdx.z;
    int t = threadIdx.x;
    int wv = t >> 6, lane = t & 63, q = lane >> 4, ln = lane & 15;
    int n0 = ny*128 + wv*32;
    __shared__ __align__(16) unsigned short patch[3*98*64]; // 36.75 KB, 128B rows
    __shared__ float lds_red[4][96];

    f32x4 acc[12];                                          // [mf*2 + j]
    #pragma unroll
    for (int i = 0; i < 12; ++i) acc[i] = (f32x4){0.f,0.f,0.f,0.f};

    int abase[6][3];
    #pragma unroll
    for (int mf = 0; mf < 6; ++mf)
        #pragma unroll
        for (int kw = 0; kw < 3; ++kw) {
            int x2 = ln + 16*mf + kw;                       // 0..97
            abase[mf][kw] = x2*64 + (q ^ (x2 & 7))*8;
        }

    const int4* gsrc = (const int4*)et_p;

    for (int c0 = 0; c0 < 256; c0 += 64) {
        __syncthreads();                                    // prior reads done
        for (int i = t; i < 2352; i += 256) {
            int kh = i / 784; int r = i - kh*784; int x2 = r >> 3; int s = r & 7;
            ((int4*)patch)[kh*784 + x2*8 + s] =
                gsrc[((size_t)(b*H2 + h + kh)*W2 + x2)*32 + (c0 >> 3) + (s ^ (x2 & 7))];
        }
        __syncthreads();                                    // writes visible
        #pragma unroll
        for (int kh = 0; kh < 3; ++kh) {
            #pragma unroll
            for (int kw = 0; kw < 3; ++kw) {
                #pragma unroll
                for (int cs = 0; cs < 64; cs += 32) {
                    short8 av[6];
                    #pragma unroll
                    for (int mf = 0; mf < 6; ++mf)
                        av[mf] = *(const short8*)&patch[kh*6272 + (abase[mf][kw] ^ cs)];
                    const unsigned short* bp = wtb
                        + (size_t)(kh*3 + kw)*65536
                        + ((size_t)(((c0 + cs) >> 3) + q)*256 + n0 + ln)*8;
                    #pragma unroll
                    for (int j = 0; j < 2; ++j) {
                        short8 bv = *(const short8*)(bp + j*128);
                        #pragma unroll
                        for (int mf = 0; mf < 6; ++mf)
                            acc[mf*2+j] = __builtin_amdgcn_mfma_f32_16x16x32_bf16(av[mf], bv, acc[mf*2+j], 0, 0, 0);
                    }
                }
            }
        }
    }

    float psum[24];
    #pragma unroll
    for (int i = 0; i < 24; ++i) psum[i] = 0.f;
    #pragma unroll
    for (int j = 0; j < 2; ++j) {
        int o = n0 + j*16 + ln;
        float inv  = bn_g[o]*rsqrtf(bn_v[o] + BN_EPS);
        float mean = bn_m[o], beta = bn_b[o], bias = cb[o], vw = v_w[o];
        #pragma unroll
        for (int mf = 0; mf < 6; ++mf)
            #pragma unroll
            for (int r = 0; r < 4; ++r) {
                float x = (acc[mf*2+j][r] + bias - mean)*inv + beta;
                x = fminf(fmaxf(x, -15.f), 15.f);
                float ex = __expf(2.f*x);
                psum[mf*4+r] += ((ex - 1.f)/(ex + 1.f))*vw;
            }
    }
    #pragma unroll
    for (int s = 1; s < 16; s <<= 1)
        #pragma unroll
        for (int i = 0; i < 24; ++i) psum[i] += __shfl_xor(psum[i], s);
    if (ln == 0) {
        #pragma unroll
        for (int mf = 0; mf < 6; ++mf)
            #pragma unroll
            for (int r = 0; r < 4; ++r)
                lds_red[wv][mf*16 + q*4 + r] = psum[mf*4+r];
    }
    __syncthreads();
    if (t < 96)
        e_part[(size_t)ny*(B*HW) + (b*H + h)*W + t] =
            lds_red[0][t] + lds_red[1][t] + lds_red[2][t] + lds_red[3][t];
}

// ---------------- K6: masked softmax over (h,w) -> alpha (sums the two e partials) ----------------
__global__ __launch_bounds__(256) void k_softmax(
    const float* e_part, const int* h_mask, const int* w_mask, const float* v_b,
    float* alpha_out)
{
    int b = blockIdx.x, t = threadIdx.x;
    int hm = h_mask[b], wm = w_mask[b];
    float vb = v_b[0];
    __shared__ float red[256];
    float vals[9];
    float loc = 0.f;
    #pragma unroll
    for (int i = 0; i < 9; ++i) {
        int hw = t + i*256;
        int hh = hw / W, ww = hw % W;
        float v = 0.f;
        if (hh < hm && ww < wm)
            v = __expf(e_part[b*HW + hw] + e_part[B*HW + b*HW + hw] + vb);
        vals[i] = v; loc += v;
    }
    red[t] = loc; __syncthreads();
    for (int s = 128; s > 0; s >>= 1) { if (t < s) red[t] += red[t+s]; __syncthreads(); }
    float inv = 1.f/(red[0] + 1e-8f);
    #pragma unroll
    for (int i = 0; i < 9; ++i) alpha_out[b*HW + t + i*256] = vals[i]*inv;
}

// ---------------- K7: ct[b,c] += sum_hw alpha[b,hw]*imgT[b,hw,c] (bf16 A, fp32 acc, atomics) ----------------
__global__ __launch_bounds__(256) void k_ct(
    const float* alpha, const unsigned short* imgT, float* ct)
{
    int s = blockIdx.x, b = blockIdx.y, t = threadIdx.x;
    int cg = (t & 127)*8, half = t >> 7;
    float acc[8];
    #pragma unroll
    for (int j = 0; j < 8; ++j) acc[j] = 0.f;
    for (int i = 0; i < 72; ++i) {
        int hw = s*144 + i*2 + half;
        float a = alpha[b*HW + hw];
        union { short8 v; unsigned short u[8]; } pk;
        pk.v = *(const short8*)&imgT[((size_t)(b*HW) + hw)*1024 + cg];
        #pragma unroll
        for (int j = 0; j < 8; ++j) acc[j] += a*bf2f(pk.u[j]);
    }
    #pragma unroll
    for (int j = 0; j < 8; ++j) atomicAdd(&ct[b*1024 + cg + j], acc[j]);
}

// ---------------- k_g2: fused GRU2 h-side+pemb | GRU2 i-side+wc (split-K) ----------------
__global__ __launch_bounds__(256) void k_g2(
    const float* st1, const int* y, const float* emb_table,
    const float* wh, const float* emb2_w, float* gh2,
    const float* ct, const float* wi, const float* wc_w, float* gi2p)
{
    int x = blockIdx.x, t = threadIdx.x;
    __shared__ float a_l[16*256];
    if (x < 56) {
        int virt = x*16;
        bool ghm = virt < 768;
        for (int i = t; i < 4096; i += 256) {
            int b = i >> 8, k = i & 255;
            a_l[i] = ghm ? st1[b*256 + k] : emb_table[y[b]*EMB + k];
        }
        __syncthreads();
        int nl = t & 15, b = t >> 4;
        float acc = 0.f;
        if (ghm) {
            int n = virt + nl;
            #pragma unroll 16
            for (int k = 0; k < 256; ++k) acc += a_l[b*256+k]*wh[k*768 + n];
        } else {
            int n = virt - 768 + nl;
            #pragma unroll 16
            for (int k = 0; k < 256; ++k) acc += a_l[b*256+k]*emb2_w[k*128 + n];
        }
        gh2[b*896 + virt + nl] = acc;
    } else {
        int xx = x - 56;
        int ks = xx / 56, virt = (xx - ks*56)*16;
        int k0 = ks*256;
        for (int i = t; i < 4096; i += 256) {
            int b = i >> 8, k = i & 255;
            a_l[i] = ct[b*1024 + k0 + k];
        }
        __syncthreads();
        int nl = t & 15, b = t >> 4;
        float acc = 0.f;
        if (virt < 768) {
            int n = virt + nl;
            #pragma unroll 16
            for (int k = 0; k < 256; ++k) acc += a_l[b*256+k]*wi[(k0+k)*768 + n];
        } else {
            int n = virt - 768 + nl;
            #pragma unroll 16
            for (int k = 0; k < 256; ++k) acc += a_l[b*256+k]*wc_w[(k0+k)*128 + n];
        }
        gi2p[(ks*16 + b)*896 + virt + nl] = acc;
    }
}

// ---------------- k_fc2c: GRU2 nonlinearity (in-block) + hidden write + pre ----------------
__global__ __launch_bounds__(256) void k_fc2c(
    const float* gi2p, const float* gh2, const float* st1,
    const float* bi, const float* bh,
    const float* fc2_w, const float* fc2_b, const float* emb2_b, const float* wc_b,
    float* hidden_out, float* pre)
{
    int n0 = blockIdx.x*16, t = threadIdx.x;
    __shared__ float st_l[16*256];
    for (int i = t; i < 4096; i += 256) {
        int b = i >> 8, k = i & 255;
        float ir = bi[k], iz = bi[256+k], in_ = bi[512+k];
        #pragma unroll
        for (int ks = 0; ks < 4; ++ks) {
            const float* g = gi2p + (ks*16 + b)*896;
            ir += g[k]; iz += g[256+k]; in_ += g[512+k];
        }
        const float* gh = gh2 + b*896;
        float hr = gh[k] + bh[k], hz = gh[256+k] + bh[256+k], hn = gh[512+k] + bh[512+k];
        float h = st1[b*256+k];
        float r = 1.f/(1.f+__expf(-(ir+hr)));
        float z = 1.f/(1.f+__expf(-(iz+hz)));
        float n = tanhf(in_ + r*hn);
        float s = (1.f - z)*n + z*h;
        st_l[i] = s;
        if (blockIdx.x == 0) hidden_out[b*HID + k] = s;
    }
    __syncthreads();
    int nl = t & 15, b = t >> 4;
    int n = n0 + nl;
    float acc = fc2_b[n] + emb2_b[n] + wc_b[n] + gh2[b*896 + 768 + n];
    #pragma unroll
    for (int ks = 0; ks < 4; ++ks) acc += gi2p[(ks*16 + b)*896 + 768 + n];
    #pragma unroll 16
    for (int k = 0; k < 256; ++k) acc += st_l[b*256+k]*fc2_w[k*128 + n];
    pre[b*128 + n] = acc;
}

// ---------------- logits (raw) = pre @ out_w + out_b ----------------
__global__ __launch_bounds__(256) void k_logits(
    const float* pre, const float* out_w, const float* out_b, float* out)
{
    int j0 = blockIdx.x*64, t = threadIdx.x;
    __shared__ float pre_l[16*128];
    for (int i = t; i < 2048; i += 256) pre_l[i] = pre[i];
    __syncthreads();
    int jl = t & 63, bg = t >> 6;
    int j = j0 + jl;
    if (j >= V) return;
    float acc0=0.f, acc1=0.f, acc2=0.f, acc3=0.f;
    const float* pl = pre_l + bg*4*128;
    #pragma unroll 8
    for (int k = 0; k < 128; ++k) {
        float wv = out_w[k*V + j];
        acc0 += pl[k]*wv; acc1 += pl[128+k]*wv; acc2 += pl[256+k]*wv; acc3 += pl[384+k]*wv;
    }
    float ob = out_b[j];
    out[(bg*4+0)*V + j] = acc0 + ob;
    out[(bg*4+1)*V + j] = acc1 + ob;
    out[(bg*4+2)*V + j] = acc2 + ob;
    out[(bg*4+3)*V + j] = acc3 + ob;
}

// ---------------- in-place log_softmax over V per batch ----------------
__global__ __launch_bounds__(1024) void k_lsm(float* out)
{
    int b = blockIdx.x, t = threadIdx.x;
    __shared__ float red[1024];
    float lg[5]; float mx = -1e30f;
    #pragma unroll
    for (int i = 0; i < 5; ++i) {
        int j = t + i*1024;
        lg[i] = (j < V) ? out[b*V + j] : -1e30f;
        mx = fmaxf(mx, lg[i]);
    }
    red[t] = mx; __syncthreads();
    for (int s = 512; s > 0; s >>= 1) { if (t < s) red[t] = fmaxf(red[t], red[t+s]); __syncthreads(); }
    float gmax = red[0]; __syncthreads();
    float se = 0.f;
    #pragma unroll
    for (int i = 0; i < 5; ++i) { int j = t + i*1024; if (j < V) se += __expf(lg[i] - gmax); }
    red[t] = se; __syncthreads();
    for (int s = 512; s > 0; s >>= 1) { if (t < s) red[t] += red[t+s]; __syncthreads(); }
    float lse = logf(red[0]);
    #pragma unroll
    for (int i = 0; i < 5; ++i) { int j = t + i*1024; if (j < V) out[b*V + j] = lg[i] - gmax - lse; }
}

extern "C" void kernel_launch(void* const* d_in, const int* in_sizes, int n_in,
                              void* d_out, int out_size, void* d_ws, size_t ws_size,
                              hipStream_t stream)
{
    const int*   input_y      = (const int*)  d_in[0];
    const float* input_hidden = (const float*)d_in[1];
    const float* img          = (const float*)d_in[2];
    const float* attention    = (const float*)d_in[4];
    const float* alpha_t      = (const float*)d_in[5];
    const int*   h_mask       = (const int*)  d_in[8];
    const int*   w_mask       = (const int*)  d_in[9];
    const float* emb_table    = (const float*)d_in[10];
    const float* gru1_wi      = (const float*)d_in[11];
    const float* gru1_wh      = (const float*)d_in[12];
    const float* gru1_bi      = (const float*)d_in[13];
    const float* gru1_bh      = (const float*)d_in[14];
    const float* fc1_w        = (const float*)d_in[15];
    const float* fc1_b        = (const float*)d_in[16];
    const float* gru2_wi      = (const float*)d_in[17];
    const float* gru2_wh      = (const float*)d_in[18];
    const float* gru2_bi      = (const float*)d_in[19];
    const float* gru2_bh      = (const float*)d_in[20];
    const float* out_w        = (const float*)d_in[21];
    const float* out_b        = (const float*)d_in[22];
    const float* emb2_w       = (const float*)d_in[23];
    const float* emb2_b       = (const float*)d_in[24];
    const float* conv1_w      = (const float*)d_in[25];
    const float* conv1_b      = (const float*)d_in[26];
    const float* conv_tan_w   = (const float*)d_in[27];
    const float* conv_tan_b   = (const float*)d_in[28];
    const float* fc2_w        = (const float*)d_in[29];
    const float* fc2_b        = (const float*)d_in[30];
    const float* ua_w         = (const float*)d_in[31];
    const float* ua_b         = (const float*)d_in[32];
    const float* uf_w         = (const float*)d_in[33];
    const float* uf_b         = (const float*)d_in[34];
    const float* v_w          = (const float*)d_in[35];
    const float* v_b          = (const float*)d_in[36];
    const float* wc_w         = (const float*)d_in[37];
    const float* wc_b         = (const float*)d_in[38];
    const float* bn1_gamma    = (const float*)d_in[39];
    const float* bn1_beta     = (const float*)d_in[40];
    const float* bn1_mean     = (const float*)d_in[41];
    const float* bn1_var      = (const float*)d_in[42];

    float* out = (float*)d_out;
    char*  ws  = (char*)d_ws;
    unsigned short* imgT = (unsigned short*)(ws + WSB_IMGT);
    unsigned short* et_p = (unsigned short*)(ws + WSB_ETP);
    unsigned short* wtb  = (unsigned short*)(ws + WSB_WTB);
    unsigned short* uat  = (unsigned short*)(ws + WSB_UAT);
    float* e_part = (float*)(ws + WSB_E);
    float* st1   = (float*)(ws + WSB_ST1);
    float* ct    = (float*)(ws + WSB_CT);
    float* pre   = (float*)(ws + WSB_PRE);
    float* gigh1 = (float*)(ws + WSB_GIGH1);
    float* gh2   = (float*)(ws + WSB_GH2);
    float* gi2p  = (float*)(ws + WSB_GI2);

    float* out_logits = out + OUT0;
    float* out_hidden = out + OUT1;
    float* out_alpha  = out + OUT2;
    float* out_attsum = out + OUT3;

    k_imgT<<<dim3(HW/64, C/128, B), 256, 0, stream>>>(img, imgT);
    k_prep<<<4024, 256, 0, stream>>>(conv_tan_w, wtb, ua_w, uat,
                                     attention, alpha_t, conv1_w, conv1_b, out_attsum,
                                     ct, et_p);
    k_tail1<<<96, 256, 0, stream>>>(input_y, emb_table, input_hidden,
                                    gru1_wi, gru1_wh, gigh1);
    k_fc1c<<<16, 256, 0, stream>>>(gigh1, input_hidden, gru1_bi, gru1_bh,
                                   fc1_w, fc1_b, st1);
    k_et<<<dim3(H, 2, B), 256, 0, stream>>>(imgT, uat, ua_b, st1, out_attsum,
                                            uf_w, uf_b, et_p);
    k_conv<<<dim3(H, 2, B), 256, 0, stream>>>(et_p, wtb, conv_tan_b,
                                              bn1_gamma, bn1_beta, bn1_mean, bn1_var,
                                              v_w, e_part);
    k_softmax<<<B, 256, 0, stream>>>(e_part, h_mask, w_mask, v_b, out_alpha);
    k_ct<<<dim3(16, B), 256, 0, stream>>>(out_alpha, imgT, ct);
    k_g2<<<280, 256, 0, stream>>>(st1, input_y, emb_table, gru2_wh, emb2_w, gh2,
                                  ct, gru2_wi, wc_w, gi2p);
    k_fc2c<<<8, 256, 0, stream>>>(gi2p, gh2, st1, gru2_bi, gru2_bh,
                                  fc2_w, fc2_b, emb2_b, wc_b, out_hidden, pre);
    k_logits<<<(V + 63)/64, 256, 0, stream>>>(pre, out_w, out_b, out_logits);
    k_lsm<<<B, 1024, 0, stream>>>(out_logits);
}